// Round 4
// baseline (231.903 us; speedup 1.0000x reference)
//
#include <hip/hip_runtime.h>
#include <hip/hip_bf16.h>

#define D 64
#define NBIN_MAX 1024   // bins = ceil(n_ent/512); n_ent <= 131072 -> <= 256
// pack layout: t[16:0] | r[22:17] | h_low[31:23]  (t<2^17, r<64, 512 ents/bin)

// ---- adaptive loads: index width (int32/int64) and float width (bf16/fp32) ----
__device__ __forceinline__ int load_idx(const void* p, long long i, int mode) {
  return mode ? (int)((const long long*)p)[i] : ((const int*)p)[i];
}
__device__ __forceinline__ float loadf(const void* p, long long i, int fm) {
  return fm ? ((const float*)p)[i]
            : __bfloat162float(((const __hip_bfloat16*)p)[i]);
}
// bf16 bit helpers
__device__ __forceinline__ unsigned short bf16bits(float v) {
  unsigned u = __float_as_uint(v);
  return (unsigned short)((u + 0x7FFFu + ((u >> 16) & 1u)) >> 16);  // RNE
}
__device__ __forceinline__ float bflo(unsigned u) { return __uint_as_float(u << 16); }
__device__ __forceinline__ float bfhi(unsigned u) { return __uint_as_float(u & 0xFFFF0000u); }

// ---------- zero bin cursors + detect dtypes (1 block) ----------
__global__ __launch_bounds__(256) void zero_detect_kernel(
    int* __restrict__ gcur, int nbins,
    const void* eidx, const void* etype, const void* ent0,
    int* __restrict__ flags, int n_edges) {
  int tid = threadIdx.x;
  for (int j = tid; j < nbins; j += 256) gcur[j] = 0;
  if (tid < 64) {
    int lane = tid;
    long long tot_e = 2LL * n_edges;
    long long step_e = tot_e / 130; if (step_e < 1) step_e = 1;
    long long pos_e = 1 + 2LL * lane * step_e;
    int ve = (pos_e < tot_e) ? ((const int*)eidx)[pos_e] : 0;
    unsigned long long be = __ballot(ve != 0);

    long long tot_t = n_edges;
    long long step_t = tot_t / 130; if (step_t < 1) step_t = 1;
    long long pos_t = 1 + 2LL * lane * step_t;
    int vt = (pos_t < tot_t) ? ((const int*)etype)[pos_t] : 0;
    unsigned long long bt = __ballot(vt != 0);

    float a = __bfloat162float(((const __hip_bfloat16*)ent0)[lane]);
    unsigned long long bf = __ballot(!(fabsf(a) <= 64.0f));  // fp32-as-bf16 => huge/nan

    if (lane == 0) {
      flags[0] = (be == 0ULL) ? 1 : 0;   // edge_index is int64
      flags[1] = (bt == 0ULL) ? 1 : 0;   // edge_type is int64
      flags[3] = (bf != 0ULL) ? 1 : 0;   // float inputs are fp32
    }
  }
}

// ---------- build pass 1: conversion + rel prep + coarse partition ----------
// Each partition block handles a 4096-edge batch: LDS count -> one global
// atomic per bin to reserve a chunk -> scatter packed edges. Chunks are ~80B
// contiguous runs owned by one block -> line-dense writes, no cross-XCD sharing.
__global__ __launch_bounds__(256) void build1_kernel(
    const void* __restrict__ ent0, const void* __restrict__ rel0,
    const void* __restrict__ eidx, const void* __restrict__ etype,
    unsigned short* __restrict__ entC, float* __restrict__ relRaw,
    float* __restrict__ relN, float* __restrict__ out_rel,
    int* __restrict__ gcur, int* __restrict__ binbuf,
    const int* __restrict__ flags,
    int ent_elems, int rel_elems, int n_ent, int n_rel, int n_edges,
    int nbins, int binCap) {
  __shared__ int s_cnt[NBIN_MAX];
  __shared__ int s_base[NBIN_MAX];
  int tid = threadIdx.x;
  int i = blockIdx.x * 256 + tid;
  int fm = flags[3];
  if (fm) {                               // fp32 inputs: convert 8 elems/thread
    int i8 = i * 8;
    if (i8 < ent_elems) {
      float4 a = ((const float4*)ent0)[i * 2];
      float4 b = ((const float4*)ent0)[i * 2 + 1];
      uint4 o;
      o.x = (unsigned)bf16bits(a.x) | ((unsigned)bf16bits(a.y) << 16);
      o.y = (unsigned)bf16bits(a.z) | ((unsigned)bf16bits(a.w) << 16);
      o.z = (unsigned)bf16bits(b.x) | ((unsigned)bf16bits(b.y) << 16);
      o.w = (unsigned)bf16bits(b.z) | ((unsigned)bf16bits(b.w) << 16);
      ((uint4*)entC)[i] = o;
    }
  }
  if (i < rel_elems) {                    // rel: raw copy + normalize + residual
    float v = loadf(rel0, i, fm);
    relRaw[i] = v;
    float ss = v * v;                     // rel_elems is a multiple of 64: whole waves
    for (int o = 32; o > 0; o >>= 1) ss += __shfl_xor(ss, o, 64);
    float nv = (ss > 0.f) ? v * rsqrtf(ss) : 0.f;
    relN[i] = nv;
    out_rel[i] = v + 3.0f * nv;           // rel_res = rel0 + 3*l2norm(rel0)
  }
  int part_blocks = (n_edges + 4095) >> 12;
  if ((int)blockIdx.x < part_blocks) {    // uniform per block: syncthreads safe
    int e0 = (int)blockIdx.x << 12;
    int m = flags[0], mr = flags[1];
    for (int b = tid; b < nbins; b += 256) s_cnt[b] = 0;
    __syncthreads();
    for (int k = 0; k < 16; ++k) {        // A: count per bin
      int e = e0 + k * 256 + tid;
      if (e < n_edges) {
        int h = load_idx(eidx, e, m);
        h = min(max(h, 0), n_ent - 1);
        atomicAdd(&s_cnt[h >> 9], 1);
      }
    }
    __syncthreads();
    for (int b = tid; b < nbins; b += 256) {  // B: reserve chunks
      int c = s_cnt[b];
      s_base[b] = c ? atomicAdd(&gcur[b], c) : 0;
      s_cnt[b] = 0;                       // reuse as running offset
    }
    __syncthreads();
    for (int k = 0; k < 16; ++k) {        // C: scatter packed edges
      int e = e0 + k * 256 + tid;
      if (e < n_edges) {
        int h = load_idx(eidx, e, m);
        int t = load_idx(eidx, (long long)n_edges + e, m);
        int r = load_idx(etype, e, mr);
        h = min(max(h, 0), n_ent - 1);
        t = min(max(t, 0), n_ent - 1);
        r = min(max(r, 0), n_rel - 1);
        int bin = h >> 9;
        int pos = s_base[bin] + atomicAdd(&s_cnt[bin], 1);
        if (pos < binCap)
          binbuf[(size_t)bin * binCap + pos] =
              t | (r << 17) | ((h & 511) << 23);
      }
    }
  }
}

// ---------- build pass 2: bin -> per-entity buckets (one block per bin) ----------
// Bin = 512 entities = line-aligned staging (C=32 or 64 ints), single-block-owned:
// all positioning via LDS atomics, zero global atomics, zero cross-XCD lines.
__global__ __launch_bounds__(256) void build2_kernel(
    const int* __restrict__ gcur, const int* __restrict__ binbuf,
    int* __restrict__ staging, int n_ent, int binCap, int C) {
  __shared__ int off2[512];
  int b = blockIdx.x;
  int tid = threadIdx.x;
  for (int j = tid; j < 512; j += 256) off2[j] = 0;
  __syncthreads();
  int cnt = min(gcur[b], binCap);
  const int* src = binbuf + (size_t)b * binCap;
  int ebase = b << 9;
  for (int e = tid; e < cnt; e += 256) {
    int pack = src[e];
    int hl = (int)(((unsigned)pack) >> 23);
    int pos = atomicAdd(&off2[hl], 1);
    if (pos < C - 1)
      staging[(size_t)(ebase + hl) * C + 1 + pos] = pack & 0x7FFFFF;
  }
  __syncthreads();
  for (int j = tid; j < 512; j += 256) {  // slot0 = count (hop clamps to C-1)
    int ent = ebase + j;
    if (ent < n_ent) staging[(size_t)ent * C] = off2[j];
  }
}

// ---------- hop core: 4 rows/wave, 16 lanes/row, 4 dims/lane ----------
// pv = preloaded slots 0..15 of this row's bucket (slot0 = count); the caller
// software-pipelines this load one row ahead. SHIFT=6: compact bf16 table
// (128B rows). SHIFT=7: strided table (256B slots, first 128B used).
template <int SHIFT>
__device__ __forceinline__ float4 hop_row_core(
    const unsigned short* __restrict__ src, const unsigned short* lds_rel,
    const int* __restrict__ adj, size_t base, int pv, int C,
    int sub, int gbase) {
  float4 acc = make_float4(0.f, 0.f, 0.f, 0.f);
  int cnt = __shfl(pv, gbase, 64);
  cnt = min(cnt, C - 1);
  int ehi = min(cnt, 15);                      // fast path: single chunk (~95%)
  for (int j = 0; j < ehi; j += 8) {
    uint2 sv[8];
    int rr[8];
#pragma unroll
    for (int k = 0; k < 8; ++k) {
      int e = j + k;
      int ee = (e < ehi) ? e : 0;              // dummy lanes replay first edge
      int p = __shfl(pv, gbase + 1 + ee, 64);
      unsigned toff = ((unsigned)(p & 0x1FFFF) << (SHIFT + 1)) + (unsigned)(sub << 3);
      rr[k] = (e < ehi) ? (int)(((unsigned)p >> 17) & 0x3F) : -1;
      sv[k] = *(const uint2*)((const char*)src + toff);
    }
#pragma unroll
    for (int k = 0; k < 8; ++k) {
      uint2 rv;
      if (rr[k] >= 0) rv = *(const uint2*)(lds_rel + (rr[k] << 6) + (sub << 2));
      else { rv.x = 0u; rv.y = 0u; }           // mask tail via zero weight
      acc.x += bflo(sv[k].x) * bflo(rv.x);
      acc.y += bfhi(sv[k].x) * bfhi(rv.x);
      acc.z += bflo(sv[k].y) * bflo(rv.y);
      acc.w += bfhi(sv[k].y) * bfhi(rv.y);
    }
  }
  if (cnt > 15) {                              // rare: subsequent chunks
    int slotbase = 16;
    int elo = 15;
    while (true) {
      int pv2 = adj[base + slotbase + sub];    // same line as chunk0 when C=32
      int eh2 = min(cnt, slotbase + 15);
      for (int j = elo; j < eh2; j += 8) {
        uint2 sv[8];
        int rr[8];
#pragma unroll
        for (int k = 0; k < 8; ++k) {
          int e = j + k;
          int ee = (e < eh2) ? e : elo;
          int p = __shfl(pv2, gbase + (1 + ee - slotbase), 64);
          unsigned toff = ((unsigned)(p & 0x1FFFF) << (SHIFT + 1)) + (unsigned)(sub << 3);
          rr[k] = (e < eh2) ? (int)(((unsigned)p >> 17) & 0x3F) : -1;
          sv[k] = *(const uint2*)((const char*)src + toff);
        }
#pragma unroll
        for (int k = 0; k < 8; ++k) {
          uint2 rv;
          if (rr[k] >= 0) rv = *(const uint2*)(lds_rel + (rr[k] << 6) + (sub << 2));
          else { rv.x = 0u; rv.y = 0u; }
          acc.x += bflo(sv[k].x) * bflo(rv.x);
          acc.y += bfhi(sv[k].x) * bfhi(rv.x);
          acc.z += bflo(sv[k].y) * bflo(rv.y);
          acc.w += bfhi(sv[k].y) * bfhi(rv.y);
        }
      }
      if (eh2 >= cnt) break;
      slotbase += 16;
      elo = slotbase - 1;
    }
  }
  return acc;
}

__device__ __forceinline__ float4 norm4(float4 acc) {
  float ss = acc.x * acc.x + acc.y * acc.y + acc.z * acc.z + acc.w * acc.w;
  for (int o = 8; o > 0; o >>= 1) ss += __shfl_xor(ss, o, 64);
  // l2_normalize(agg/denom) == l2_normalize(agg): denom positive scalar per row
  float inv = (ss > 0.f) ? rsqrtf(ss) : 0.f;
  return make_float4(acc.x * inv, acc.y * inv, acc.z * inv, acc.w * inv);
}

// hop0: gather bf16 (ent0 or entC) -> v0 bf16, strided into out_ent row slots
__global__ __launch_bounds__(256, 8) void hop0_kernel(
    const unsigned short* __restrict__ srcRaw, const unsigned short* __restrict__ srcConv,
    const float* __restrict__ relX, const int* __restrict__ staging,
    const int* __restrict__ flags,
    unsigned short* __restrict__ v0out /*out_ent as bf16, stride 128 elems/row*/,
    int n_ent, int n_rel, int C) {
  extern __shared__ unsigned short lds_rel[];
  for (int i = threadIdx.x; i < n_rel * D; i += blockDim.x)
    lds_rel[i] = bf16bits(relX[i]);
  __syncthreads();
  const unsigned short* src = flags[3] ? srcConv : srcRaw;
  int lane = threadIdx.x & 63;
  int sub = lane & 15;
  int grp = (lane >> 4) & 3;
  int gbase = lane & 48;
  int wid = (blockIdx.x * blockDim.x + threadIdx.x) >> 6;
  int nw = (gridDim.x * blockDim.x) >> 6;
  int step = nw * 4;
  int row = wid * 4 + grp;
  if (row >= n_ent) return;
  size_t base = (size_t)row * C;
  int pv = staging[base + sub];
  while (row < n_ent) {
    int nrow = row + step;
    size_t nbase = (size_t)nrow * C;
    int pv_next = (nrow < n_ent) ? staging[nbase + sub] : 0;  // prefetch next row
    float4 val = norm4(hop_row_core<6>(src, lds_rel, staging, base, pv, C, sub, gbase));
    uint2 o;
    o.x = (unsigned)bf16bits(val.x) | ((unsigned)bf16bits(val.y) << 16);
    o.y = (unsigned)bf16bits(val.z) | ((unsigned)bf16bits(val.w) << 16);
    *(uint2*)(v0out + ((size_t)row << 7) + (sub << 2)) = o;   // strided: 256B slots
    row = nrow; base = nbase; pv = pv_next;
  }
}

// hop1: gather v0 (strided bf16 in out_ent) -> v1 bf16 compact into entA
__global__ __launch_bounds__(256, 8) void hop1_kernel(
    const unsigned short* __restrict__ v0, const float* __restrict__ relX,
    const int* __restrict__ staging,
    unsigned short* __restrict__ dst, int n_ent, int n_rel, int C) {
  extern __shared__ unsigned short lds_rel[];
  for (int i = threadIdx.x; i < n_rel * D; i += blockDim.x)
    lds_rel[i] = bf16bits(relX[i]);
  __syncthreads();
  int lane = threadIdx.x & 63;
  int sub = lane & 15;
  int grp = (lane >> 4) & 3;
  int gbase = lane & 48;
  int wid = (blockIdx.x * blockDim.x + threadIdx.x) >> 6;
  int nw = (gridDim.x * blockDim.x) >> 6;
  int step = nw * 4;
  int row = wid * 4 + grp;
  if (row >= n_ent) return;
  size_t base = (size_t)row * C;
  int pv = staging[base + sub];
  while (row < n_ent) {
    int nrow = row + step;
    size_t nbase = (size_t)nrow * C;
    int pv_next = (nrow < n_ent) ? staging[nbase + sub] : 0;  // prefetch next row
    float4 val = norm4(hop_row_core<7>(v0, lds_rel, staging, base, pv, C, sub, gbase));
    uint2 o;
    o.x = (unsigned)bf16bits(val.x) | ((unsigned)bf16bits(val.y) << 16);
    o.y = (unsigned)bf16bits(val.z) | ((unsigned)bf16bits(val.w) << 16);
    *(uint2*)(dst + ((size_t)row << 6) + (sub << 2)) = o;
    row = nrow; base = nbase; pv = pv_next;
  }
}

// hop2: gather bf16 v1 (entA) -> v2; out = base + v0 + v1 + v2.
// v0 is read linearly from this row's own slot of out_ent BEFORE overwriting it
// (same lanes, same bytes -> no cross-thread hazard). NOTE: out_ent deliberately
// not __restrict__ (aliases the v0 table).
__global__ __launch_bounds__(256, 8) void hop2_kernel(
    const unsigned short* __restrict__ v1tab, const float* __restrict__ relX,
    const int* __restrict__ staging,
    const void* __restrict__ ent0, const void* __restrict__ drug0,
    const int* __restrict__ flags,
    float* out_ent, float* __restrict__ out_drug,
    int n_ent, int n_drugs, int n_rel, int C) {
  extern __shared__ unsigned short lds_rel[];
  for (int i = threadIdx.x; i < n_rel * D; i += blockDim.x)
    lds_rel[i] = bf16bits(relX[i]);
  __syncthreads();
  int fm = flags[3];
  int lane = threadIdx.x & 63;
  int sub = lane & 15;
  int grp = (lane >> 4) & 3;
  int gbase = lane & 48;
  int wid = (blockIdx.x * blockDim.x + threadIdx.x) >> 6;
  int nw = (gridDim.x * blockDim.x) >> 6;
  int step = nw * 4;
  int row = wid * 4 + grp;
  if (row >= n_ent) return;
  size_t base = (size_t)row * C;
  int pv = staging[base + sub];
  while (row < n_ent) {
    int nrow = row + step;
    size_t nbase = (size_t)nrow * C;
    int pv_next = (nrow < n_ent) ? staging[nbase + sub] : 0;  // prefetch next row
    float4 val = norm4(hop_row_core<6>(v1tab, lds_rel, staging, base, pv, C, sub, gbase));
    size_t eoff = ((size_t)row << 6) + (sub << 2);
    uint2 b0 = *(const uint2*)((const unsigned short*)out_ent +
                               ((size_t)row << 7) + (sub << 2));  // v0 (bf16, strided)
    uint2 b1 = *(const uint2*)(v1tab + eoff);                     // v1 (bf16)
    float4 s;
    s.x = val.x + bflo(b0.x) + bflo(b1.x);
    s.y = val.y + bfhi(b0.x) + bfhi(b1.x);
    s.z = val.z + bflo(b0.y) + bflo(b1.y);
    s.w = val.w + bfhi(b0.y) + bfhi(b1.y);
    float4 basev;
    if (fm) basev = *(const float4*)((const float*)ent0 + eoff);
    else {
      uint2 bb = *(const uint2*)((const unsigned short*)ent0 + eoff);
      basev = make_float4(bflo(bb.x), bfhi(bb.x), bflo(bb.y), bfhi(bb.y));
    }
    *(float4*)(out_ent + eoff) =
        make_float4(basev.x + s.x, basev.y + s.y, basev.z + s.z, basev.w + s.w);
    if (row < n_drugs) {
      float4 db;
      if (fm) db = *(const float4*)((const float*)drug0 + eoff);
      else {
        uint2 bb = *(const uint2*)((const unsigned short*)drug0 + eoff);
        db = make_float4(bflo(bb.x), bfhi(bb.x), bflo(bb.y), bfhi(bb.y));
      }
      *(float4*)(out_drug + eoff) =
          make_float4(db.x + s.x, db.y + s.y, db.z + s.z, db.w + s.w);
    }
    row = nrow; base = nbase; pv = pv_next;
  }
}

__global__ void mini_flag_kernel(float* out, int hostbits) {
  if (blockIdx.x == 0 && threadIdx.x == 0)
    out[0] = 64.0f * (float)hostbits;
}

extern "C" void kernel_launch(void* const* d_in, const int* in_sizes, int n_in,
                              void* d_out, int out_size, void* d_ws, size_t ws_size,
                              hipStream_t stream) {
  const void* ent0  = d_in[0];
  const void* drug0 = d_in[1];
  const void* rel0  = d_in[2];
  const void* eidx  = d_in[3];
  const void* etype = d_in[4];
  float* out = (float*)d_out;          // output is fp32 (verified)

  const int ent_elems  = in_sizes[0];
  const int drug_elems = in_sizes[1];
  const int rel_elems  = in_sizes[2];
  const int n_edges    = in_sizes[4];
  const int n_ent   = ent_elems / D;
  const int n_drugs = drug_elems / D;
  const int n_rel   = rel_elems / D;

  const int nbins  = (n_ent + 511) >> 9;
  const int binCap = (nbins > 0) ? ent_elems / nbins : 0;  // binbuf fits in out_ent
  const long long expected = (nbins > 0) ? (n_edges + nbins - 1) / nbins : 0;

  int hostbits = 0;
  bool sizes_ok = (n_in == 5) &&
                  (in_sizes[3] == 2 * n_edges) &&
                  (out_size == ent_elems + drug_elems + rel_elems) &&
                  (ent_elems % D == 0) && (drug_elems % D == 0) &&
                  (rel_elems % D == 0) && (n_ent > 0) && (n_edges > 0) &&
                  (n_ent <= 131072) && (n_rel >= 1) && (n_rel <= 64) &&
                  (n_drugs <= n_ent) && (nbins <= NBIN_MAX) &&
                  ((long long)binCap >= 2 * expected + 1024);
  if (!sizes_ok) hostbits |= 32;

  char* w = (char*)d_ws;
  auto alloc = [&](size_t bytes) {
    char* p = w;
    w += (bytes + 255) / 256 * 256;
    return p;
  };
  int* flags    = (int*)alloc(256);
  int* gcur     = (int*)alloc((size_t)NBIN_MAX * 4);
  float* relRaw = (float*)alloc((size_t)(rel_elems > 0 ? rel_elems : 1) * 4);
  float* relN   = (float*)alloc((size_t)(rel_elems > 0 ? rel_elems : 1) * 4);
  unsigned short* entA = (unsigned short*)alloc((size_t)(ent_elems > 0 ? ent_elems : 1) * 2);
  size_t fixed = (size_t)(w - (char*)d_ws);
  // bucket stride C: LINE-ALIGNED (64 or 32 ints = 256/128 B). Capacity C-1.
  // C=32 capacity 31: Poisson(10) tail P(deg>31) ~ 1.6e-9/row; dataset max ~27.
  long long avail = (ws_size > fixed + 512) ? (long long)(ws_size - fixed - 512) : 0;
  int C = 0;
  if (n_ent > 0) {
    if (avail >= (long long)n_ent * 64 * 4) C = 64;
    else if (avail >= (long long)n_ent * 32 * 4) C = 32;
  }
  if (C == 0) hostbits |= 16;
  int* staging = (int*)alloc(((size_t)(n_ent > 0 ? n_ent : 1) * (size_t)(C > 0 ? C : 1) + 64) * 4);
  unsigned short* entC = entA;  // conversion buffer: dead before hop1 writes entA
  int* binbuf = (int*)out;      // coarse-bin buffer lives in d_out (dead until hop0)

  if (hostbits) {
    mini_flag_kernel<<<1, 64, 0, stream>>>(out, hostbits);
    return;
  }

  float* out_ent  = out;
  float* out_drug = out + ent_elems;
  float* out_rel  = out + ent_elems + drug_elems;

  zero_detect_kernel<<<1, 256, 0, stream>>>(
      gcur, nbins, eidx, etype, ent0, flags, n_edges);

  int conv_blocks = (ent_elems / 8 + 255) / 256;
  int part_blocks = (n_edges + 4095) >> 12;
  int rel_blocks  = (rel_elems + 255) / 256;
  int g1 = conv_blocks;
  if (part_blocks > g1) g1 = part_blocks;
  if (rel_blocks > g1) g1 = rel_blocks;
  build1_kernel<<<g1, 256, 0, stream>>>(
      ent0, rel0, eidx, etype, entC, relRaw, relN, out_rel,
      gcur, binbuf, flags, ent_elems, rel_elems, n_ent, n_rel, n_edges,
      nbins, binCap);

  build2_kernel<<<nbins, 256, 0, stream>>>(
      gcur, binbuf, staging, n_ent, binCap, C);

  size_t lds_bytes = (size_t)n_rel * D * 2;  // bf16 rel table, 6.5 KB
  int hop_blocks = 4096;
  // hop0: ent0/entC -> v0 bf16 (strided in out_ent); hop1: v0 -> entA (v1 bf16);
  // hop2: entA gather + v0/v1 linear + ent0 -> final out
  hop0_kernel<<<hop_blocks, 256, lds_bytes, stream>>>(
      (const unsigned short*)ent0, entC, relRaw, staging, flags,
      (unsigned short*)out_ent, n_ent, n_rel, C);
  hop1_kernel<<<hop_blocks, 256, lds_bytes, stream>>>(
      (const unsigned short*)out_ent, relN, staging, entA, n_ent, n_rel, C);
  hop2_kernel<<<hop_blocks, 256, lds_bytes, stream>>>(
      entA, relN, staging, ent0, drug0, flags,
      out_ent, out_drug, n_ent, n_drugs, n_rel, C);
}

// Round 5
// 205.735 us; speedup vs baseline: 1.1272x; 1.1272x over previous
//
#include <hip/hip_runtime.h>
#include <hip/hip_bf16.h>

#define D 64
#define NBIN_MAX 1024   // bins = ceil(n_ent/512); n_ent <= 131072 -> <= 256
// pack layout: t[16:0] | r[22:17] | h_low[31:23]  (t<2^17, r<64, 512 ents/bin)

// ---- adaptive loads: index width (int32/int64) and float width (bf16/fp32) ----
__device__ __forceinline__ int load_idx(const void* p, long long i, int mode) {
  return mode ? (int)((const long long*)p)[i] : ((const int*)p)[i];
}
__device__ __forceinline__ float loadf(const void* p, long long i, int fm) {
  return fm ? ((const float*)p)[i]
            : __bfloat162float(((const __hip_bfloat16*)p)[i]);
}
// bf16 bit helpers
__device__ __forceinline__ unsigned short bf16bits(float v) {
  unsigned u = __float_as_uint(v);
  return (unsigned short)((u + 0x7FFFu + ((u >> 16) & 1u)) >> 16);  // RNE
}
__device__ __forceinline__ float bflo(unsigned u) { return __uint_as_float(u << 16); }
__device__ __forceinline__ float bfhi(unsigned u) { return __uint_as_float(u & 0xFFFF0000u); }

// non-temporal helpers (stream hints: don't pollute L2 gather working set)
typedef float v4f __attribute__((ext_vector_type(4)));
typedef unsigned v2u __attribute__((ext_vector_type(2)));
__device__ __forceinline__ float4 ntload_f4(const float* p) {
  v4f t = __builtin_nontemporal_load((const v4f*)p);
  return make_float4(t.x, t.y, t.z, t.w);
}
__device__ __forceinline__ uint2 ntload_u2(const void* p) {
  v2u t = __builtin_nontemporal_load((const v2u*)p);
  uint2 r; r.x = t.x; r.y = t.y; return r;
}
__device__ __forceinline__ void ntstore_f4(float* p, float4 v) {
  v4f t; t.x = v.x; t.y = v.y; t.z = v.z; t.w = v.w;
  __builtin_nontemporal_store(t, (v4f*)p);
}

// ---------- zero bin cursors + detect dtypes (1 block) ----------
__global__ __launch_bounds__(256) void zero_detect_kernel(
    int* __restrict__ gcur, int nbins,
    const void* eidx, const void* etype, const void* ent0,
    int* __restrict__ flags, int n_edges) {
  int tid = threadIdx.x;
  for (int j = tid; j < nbins; j += 256) gcur[j] = 0;
  if (tid < 64) {
    int lane = tid;
    long long tot_e = 2LL * n_edges;
    long long step_e = tot_e / 130; if (step_e < 1) step_e = 1;
    long long pos_e = 1 + 2LL * lane * step_e;
    int ve = (pos_e < tot_e) ? ((const int*)eidx)[pos_e] : 0;
    unsigned long long be = __ballot(ve != 0);

    long long tot_t = n_edges;
    long long step_t = tot_t / 130; if (step_t < 1) step_t = 1;
    long long pos_t = 1 + 2LL * lane * step_t;
    int vt = (pos_t < tot_t) ? ((const int*)etype)[pos_t] : 0;
    unsigned long long bt = __ballot(vt != 0);

    float a = __bfloat162float(((const __hip_bfloat16*)ent0)[lane]);
    unsigned long long bf = __ballot(!(fabsf(a) <= 64.0f));  // fp32-as-bf16 => huge/nan

    if (lane == 0) {
      flags[0] = (be == 0ULL) ? 1 : 0;   // edge_index is int64
      flags[1] = (bt == 0ULL) ? 1 : 0;   // edge_type is int64
      flags[3] = (bf != 0ULL) ? 1 : 0;   // float inputs are fp32
    }
  }
}

// ---------- build pass 1: conversion + rel prep + coarse partition ----------
__global__ __launch_bounds__(256) void build1_kernel(
    const void* __restrict__ ent0, const void* __restrict__ rel0,
    const void* __restrict__ eidx, const void* __restrict__ etype,
    unsigned short* __restrict__ entC, float* __restrict__ relRaw,
    float* __restrict__ relN, float* __restrict__ out_rel,
    int* __restrict__ gcur, int* __restrict__ binbuf,
    const int* __restrict__ flags,
    int ent_elems, int rel_elems, int n_ent, int n_rel, int n_edges,
    int nbins, int binCap) {
  __shared__ int s_cnt[NBIN_MAX];
  __shared__ int s_base[NBIN_MAX];
  int tid = threadIdx.x;
  int i = blockIdx.x * 256 + tid;
  int fm = flags[3];
  if (fm) {                               // fp32 inputs: convert 8 elems/thread
    int i8 = i * 8;
    if (i8 < ent_elems) {
      float4 a = ((const float4*)ent0)[i * 2];
      float4 b = ((const float4*)ent0)[i * 2 + 1];
      uint4 o;
      o.x = (unsigned)bf16bits(a.x) | ((unsigned)bf16bits(a.y) << 16);
      o.y = (unsigned)bf16bits(a.z) | ((unsigned)bf16bits(a.w) << 16);
      o.z = (unsigned)bf16bits(b.x) | ((unsigned)bf16bits(b.y) << 16);
      o.w = (unsigned)bf16bits(b.z) | ((unsigned)bf16bits(b.w) << 16);
      ((uint4*)entC)[i] = o;
    }
  }
  if (i < rel_elems) {                    // rel: raw copy + normalize + residual
    float v = loadf(rel0, i, fm);
    relRaw[i] = v;
    float ss = v * v;                     // rel_elems is a multiple of 64: whole waves
    for (int o = 32; o > 0; o >>= 1) ss += __shfl_xor(ss, o, 64);
    float nv = (ss > 0.f) ? v * rsqrtf(ss) : 0.f;
    relN[i] = nv;
    out_rel[i] = v + 3.0f * nv;           // rel_res = rel0 + 3*l2norm(rel0)
  }
  int part_blocks = (n_edges + 4095) >> 12;
  if ((int)blockIdx.x < part_blocks) {    // uniform per block: syncthreads safe
    int e0 = (int)blockIdx.x << 12;
    int m = flags[0], mr = flags[1];
    for (int b = tid; b < nbins; b += 256) s_cnt[b] = 0;
    __syncthreads();
    for (int k = 0; k < 16; ++k) {        // A: count per bin
      int e = e0 + k * 256 + tid;
      if (e < n_edges) {
        int h = load_idx(eidx, e, m);
        h = min(max(h, 0), n_ent - 1);
        atomicAdd(&s_cnt[h >> 9], 1);
      }
    }
    __syncthreads();
    for (int b = tid; b < nbins; b += 256) {  // B: reserve chunks
      int c = s_cnt[b];
      s_base[b] = c ? atomicAdd(&gcur[b], c) : 0;
      s_cnt[b] = 0;                       // reuse as running offset
    }
    __syncthreads();
    for (int k = 0; k < 16; ++k) {        // C: scatter packed edges
      int e = e0 + k * 256 + tid;
      if (e < n_edges) {
        int h = load_idx(eidx, e, m);
        int t = load_idx(eidx, (long long)n_edges + e, m);
        int r = load_idx(etype, e, mr);
        h = min(max(h, 0), n_ent - 1);
        t = min(max(t, 0), n_ent - 1);
        r = min(max(r, 0), n_rel - 1);
        int bin = h >> 9;
        int pos = s_base[bin] + atomicAdd(&s_cnt[bin], 1);
        if (pos < binCap)
          binbuf[(size_t)bin * binCap + pos] =
              t | (r << 17) | ((h & 511) << 23);
      }
    }
  }
}

// ---------- build pass 2: bin -> per-entity buckets (one block per bin) ----------
__global__ __launch_bounds__(256) void build2_kernel(
    const int* __restrict__ gcur, const int* __restrict__ binbuf,
    int* __restrict__ staging, int n_ent, int binCap, int C) {
  __shared__ int off2[512];
  int b = blockIdx.x;
  int tid = threadIdx.x;
  for (int j = tid; j < 512; j += 256) off2[j] = 0;
  __syncthreads();
  int cnt = min(gcur[b], binCap);
  const int* src = binbuf + (size_t)b * binCap;
  int ebase = b << 9;
  for (int e = tid; e < cnt; e += 256) {
    int pack = src[e];
    int hl = (int)(((unsigned)pack) >> 23);
    int pos = atomicAdd(&off2[hl], 1);
    if (pos < C - 1)
      staging[(size_t)(ebase + hl) * C + 1 + pos] = pack & 0x7FFFFF;
  }
  __syncthreads();
  for (int j = tid; j < 512; j += 256) {  // slot0 = count (hop clamps to C-1)
    int ent = ebase + j;
    if (ent < n_ent) staging[(size_t)ent * C] = off2[j];
  }
}

// ---------- hop core: 4 rows/wave, 16 lanes/row, 4 dims/lane ----------
// pv = preloaded slots 0..15 (slot0 = count); caller prefetches one row ahead.
// lds_rel is fp32 with a ZERO row at index zr (= n_rel): dummy/tail fragments
// read the zero row instead of branching. SHIFT=6: compact bf16 table (128B
// rows). SHIFT=7: strided table (256B slots, first 128B used).
template <int SHIFT>
__device__ __forceinline__ float4 hop_row_core(
    const unsigned short* __restrict__ src, const float* lds_rel,
    const int* __restrict__ adj, size_t base, int pv, int C, int zr,
    int sub, int gbase) {
  float4 acc = make_float4(0.f, 0.f, 0.f, 0.f);
  int cnt = __shfl(pv, gbase, 64);
  cnt = min(cnt, C - 1);
  int ehi = min(cnt, 15);                      // fast path: single chunk (~95%)
  for (int j = 0; j < ehi; j += 8) {
    uint2 sv[8];
    int rr[8];
#pragma unroll
    for (int k = 0; k < 8; ++k) {
      int e = j + k;
      int ee = (e < ehi) ? e : 0;              // dummy lanes replay first edge
      int p = __shfl(pv, gbase + 1 + ee, 64);
      unsigned toff = ((unsigned)(p & 0x1FFFF) << (SHIFT + 1)) + (unsigned)(sub << 3);
      rr[k] = (e < ehi) ? (int)(((unsigned)p >> 17) & 0x3F) : zr;
      sv[k] = *(const uint2*)((const char*)src + toff);
    }
#pragma unroll
    for (int k = 0; k < 8; ++k) {
      float4 rv = *(const float4*)(lds_rel + (rr[k] << 6) + (sub << 2));
      acc.x += bflo(sv[k].x) * rv.x;
      acc.y += bfhi(sv[k].x) * rv.y;
      acc.z += bflo(sv[k].y) * rv.z;
      acc.w += bfhi(sv[k].y) * rv.w;
    }
  }
  if (cnt > 15) {                              // rare: subsequent chunks
    int slotbase = 16;
    int elo = 15;
    while (true) {
      int pv2 = adj[base + slotbase + sub];
      int eh2 = min(cnt, slotbase + 15);
      for (int j = elo; j < eh2; j += 8) {
        uint2 sv[8];
        int rr[8];
#pragma unroll
        for (int k = 0; k < 8; ++k) {
          int e = j + k;
          int ee = (e < eh2) ? e : elo;
          int p = __shfl(pv2, gbase + (1 + ee - slotbase), 64);
          unsigned toff = ((unsigned)(p & 0x1FFFF) << (SHIFT + 1)) + (unsigned)(sub << 3);
          rr[k] = (e < eh2) ? (int)(((unsigned)p >> 17) & 0x3F) : zr;
          sv[k] = *(const uint2*)((const char*)src + toff);
        }
#pragma unroll
        for (int k = 0; k < 8; ++k) {
          float4 rv = *(const float4*)(lds_rel + (rr[k] << 6) + (sub << 2));
          acc.x += bflo(sv[k].x) * rv.x;
          acc.y += bfhi(sv[k].x) * rv.y;
          acc.z += bflo(sv[k].y) * rv.z;
          acc.w += bfhi(sv[k].y) * rv.w;
        }
      }
      if (eh2 >= cnt) break;
      slotbase += 16;
      elo = slotbase - 1;
    }
  }
  return acc;
}

__device__ __forceinline__ float4 norm4(float4 acc) {
  float ss = acc.x * acc.x + acc.y * acc.y + acc.z * acc.z + acc.w * acc.w;
  for (int o = 8; o > 0; o >>= 1) ss += __shfl_xor(ss, o, 64);
  // l2_normalize(agg/denom) == l2_normalize(agg): denom positive scalar per row
  float inv = (ss > 0.f) ? rsqrtf(ss) : 0.f;
  return make_float4(acc.x * inv, acc.y * inv, acc.z * inv, acc.w * inv);
}

// shared LDS fill: fp32 rel table + zero row at index n_rel
__device__ __forceinline__ void fill_rel_lds(float* lds_rel, const float* relX,
                                             int n_rel) {
  int tot = (n_rel + 1) * D;
  for (int i = threadIdx.x; i < tot; i += blockDim.x)
    lds_rel[i] = (i < n_rel * D) ? relX[i] : 0.f;
  __syncthreads();
}

// hop0: gather bf16 (ent0 or entC) -> v0 bf16, strided into out_ent row slots
__global__ __launch_bounds__(256, 8) void hop0_kernel(
    const unsigned short* __restrict__ srcRaw, const unsigned short* __restrict__ srcConv,
    const float* __restrict__ relX, const int* __restrict__ staging,
    const int* __restrict__ flags,
    unsigned short* __restrict__ v0out /*out_ent as bf16, stride 128 elems/row*/,
    int n_ent, int n_rel, int C) {
  extern __shared__ float lds_rel[];
  fill_rel_lds(lds_rel, relX, n_rel);
  const unsigned short* src = flags[3] ? srcConv : srcRaw;
  int lane = threadIdx.x & 63;
  int sub = lane & 15;
  int grp = (lane >> 4) & 3;
  int gbase = lane & 48;
  int wid = (blockIdx.x * blockDim.x + threadIdx.x) >> 6;
  int nw = (gridDim.x * blockDim.x) >> 6;
  int step = nw * 4;
  int row = wid * 4 + grp;
  if (row >= n_ent) return;
  size_t base = (size_t)row * C;
  int pv = staging[base + sub];
  while (row < n_ent) {
    int nrow = row + step;
    size_t nbase = (size_t)nrow * C;
    int pv_next = (nrow < n_ent) ? staging[nbase + sub] : 0;  // prefetch next row
    float4 val = norm4(hop_row_core<6>(src, lds_rel, staging, base, pv, C, n_rel, sub, gbase));
    uint2 o;
    o.x = (unsigned)bf16bits(val.x) | ((unsigned)bf16bits(val.y) << 16);
    o.y = (unsigned)bf16bits(val.z) | ((unsigned)bf16bits(val.w) << 16);
    *(uint2*)(v0out + ((size_t)row << 7) + (sub << 2)) = o;   // strided: 256B slots
    row = nrow; base = nbase; pv = pv_next;
  }
}

// hop1: gather v0 (strided bf16 in out_ent) -> v1 bf16 compact into entA
__global__ __launch_bounds__(256, 8) void hop1_kernel(
    const unsigned short* __restrict__ v0, const float* __restrict__ relX,
    const int* __restrict__ staging,
    unsigned short* __restrict__ dst, int n_ent, int n_rel, int C) {
  extern __shared__ float lds_rel[];
  fill_rel_lds(lds_rel, relX, n_rel);
  int lane = threadIdx.x & 63;
  int sub = lane & 15;
  int grp = (lane >> 4) & 3;
  int gbase = lane & 48;
  int wid = (blockIdx.x * blockDim.x + threadIdx.x) >> 6;
  int nw = (gridDim.x * blockDim.x) >> 6;
  int step = nw * 4;
  int row = wid * 4 + grp;
  if (row >= n_ent) return;
  size_t base = (size_t)row * C;
  int pv = staging[base + sub];
  while (row < n_ent) {
    int nrow = row + step;
    size_t nbase = (size_t)nrow * C;
    int pv_next = (nrow < n_ent) ? staging[nbase + sub] : 0;  // prefetch next row
    float4 val = norm4(hop_row_core<7>(v0, lds_rel, staging, base, pv, C, n_rel, sub, gbase));
    uint2 o;
    o.x = (unsigned)bf16bits(val.x) | ((unsigned)bf16bits(val.y) << 16);
    o.y = (unsigned)bf16bits(val.z) | ((unsigned)bf16bits(val.w) << 16);
    *(uint2*)(dst + ((size_t)row << 6) + (sub << 2)) = o;
    row = nrow; base = nbase; pv = pv_next;
  }
}

// hop2: gather bf16 v1 (entA) -> v2; out = base + v0 + v1 + v2.
// v0 is read linearly from this row's own slot of out_ent BEFORE overwriting it
// (same lanes, same bytes -> no cross-thread hazard). Streaming accesses use
// non-temporal hints so they don't evict the v1 gather table from L2.
__global__ __launch_bounds__(256, 8) void hop2_kernel(
    const unsigned short* __restrict__ v1tab, const float* __restrict__ relX,
    const int* __restrict__ staging,
    const void* __restrict__ ent0, const void* __restrict__ drug0,
    const int* __restrict__ flags,
    float* out_ent, float* __restrict__ out_drug,
    int n_ent, int n_drugs, int n_rel, int C) {
  extern __shared__ float lds_rel[];
  fill_rel_lds(lds_rel, relX, n_rel);
  int fm = flags[3];
  int lane = threadIdx.x & 63;
  int sub = lane & 15;
  int grp = (lane >> 4) & 3;
  int gbase = lane & 48;
  int wid = (blockIdx.x * blockDim.x + threadIdx.x) >> 6;
  int nw = (gridDim.x * blockDim.x) >> 6;
  int step = nw * 4;
  int row = wid * 4 + grp;
  if (row >= n_ent) return;
  size_t base = (size_t)row * C;
  int pv = staging[base + sub];
  while (row < n_ent) {
    int nrow = row + step;
    size_t nbase = (size_t)nrow * C;
    int pv_next = (nrow < n_ent) ? staging[nbase + sub] : 0;  // prefetch next row
    float4 val = norm4(hop_row_core<6>(v1tab, lds_rel, staging, base, pv, C, n_rel, sub, gbase));
    size_t eoff = ((size_t)row << 6) + (sub << 2);
    uint2 b0 = ntload_u2((const unsigned short*)out_ent +
                         ((size_t)row << 7) + (sub << 2));    // v0 (bf16, strided)
    uint2 b1 = *(const uint2*)(v1tab + eoff);                 // v1 (temporal: gather table)
    float4 s;
    s.x = val.x + bflo(b0.x) + bflo(b1.x);
    s.y = val.y + bfhi(b0.x) + bfhi(b1.x);
    s.z = val.z + bflo(b0.y) + bflo(b1.y);
    s.w = val.w + bfhi(b0.y) + bfhi(b1.y);
    float4 basev;
    if (fm) basev = ntload_f4((const float*)ent0 + eoff);
    else {
      uint2 bb = ntload_u2((const unsigned short*)ent0 + eoff);
      basev = make_float4(bflo(bb.x), bfhi(bb.x), bflo(bb.y), bfhi(bb.y));
    }
    ntstore_f4(out_ent + eoff,
               make_float4(basev.x + s.x, basev.y + s.y, basev.z + s.z, basev.w + s.w));
    if (row < n_drugs) {
      float4 db;
      if (fm) db = ntload_f4((const float*)drug0 + eoff);
      else {
        uint2 bb = ntload_u2((const unsigned short*)drug0 + eoff);
        db = make_float4(bflo(bb.x), bfhi(bb.x), bflo(bb.y), bfhi(bb.y));
      }
      ntstore_f4(out_drug + eoff,
                 make_float4(db.x + s.x, db.y + s.y, db.z + s.z, db.w + s.w));
    }
    row = nrow; base = nbase; pv = pv_next;
  }
}

__global__ void mini_flag_kernel(float* out, int hostbits) {
  if (blockIdx.x == 0 && threadIdx.x == 0)
    out[0] = 64.0f * (float)hostbits;
}

extern "C" void kernel_launch(void* const* d_in, const int* in_sizes, int n_in,
                              void* d_out, int out_size, void* d_ws, size_t ws_size,
                              hipStream_t stream) {
  const void* ent0  = d_in[0];
  const void* drug0 = d_in[1];
  const void* rel0  = d_in[2];
  const void* eidx  = d_in[3];
  const void* etype = d_in[4];
  float* out = (float*)d_out;          // output is fp32 (verified)

  const int ent_elems  = in_sizes[0];
  const int drug_elems = in_sizes[1];
  const int rel_elems  = in_sizes[2];
  const int n_edges    = in_sizes[4];
  const int n_ent   = ent_elems / D;
  const int n_drugs = drug_elems / D;
  const int n_rel   = rel_elems / D;

  const int nbins  = (n_ent + 511) >> 9;
  const int binCap = (nbins > 0) ? ent_elems / nbins : 0;  // binbuf fits in out_ent
  const long long expected = (nbins > 0) ? (n_edges + nbins - 1) / nbins : 0;

  int hostbits = 0;
  bool sizes_ok = (n_in == 5) &&
                  (in_sizes[3] == 2 * n_edges) &&
                  (out_size == ent_elems + drug_elems + rel_elems) &&
                  (ent_elems % D == 0) && (drug_elems % D == 0) &&
                  (rel_elems % D == 0) && (n_ent > 0) && (n_edges > 0) &&
                  (n_ent <= 131072) && (n_rel >= 1) && (n_rel <= 64) &&
                  (n_drugs <= n_ent) && (nbins <= NBIN_MAX) &&
                  ((long long)binCap >= 2 * expected + 1024);
  if (!sizes_ok) hostbits |= 32;

  char* w = (char*)d_ws;
  auto alloc = [&](size_t bytes) {
    char* p = w;
    w += (bytes + 255) / 256 * 256;
    return p;
  };
  int* flags    = (int*)alloc(256);
  int* gcur     = (int*)alloc((size_t)NBIN_MAX * 4);
  float* relRaw = (float*)alloc((size_t)(rel_elems > 0 ? rel_elems : 1) * 4);
  float* relN   = (float*)alloc((size_t)(rel_elems > 0 ? rel_elems : 1) * 4);
  unsigned short* entA = (unsigned short*)alloc((size_t)(ent_elems > 0 ? ent_elems : 1) * 2);
  size_t fixed = (size_t)(w - (char*)d_ws);
  // bucket stride C: LINE-ALIGNED (64 or 32 ints = 256/128 B). Capacity C-1.
  // C=32 capacity 31: Poisson(10) tail P(deg>31) ~ 1.6e-9/row; dataset max ~27.
  long long avail = (ws_size > fixed + 512) ? (long long)(ws_size - fixed - 512) : 0;
  int C = 0;
  if (n_ent > 0) {
    if (avail >= (long long)n_ent * 64 * 4) C = 64;
    else if (avail >= (long long)n_ent * 32 * 4) C = 32;
  }
  if (C == 0) hostbits |= 16;
  int* staging = (int*)alloc(((size_t)(n_ent > 0 ? n_ent : 1) * (size_t)(C > 0 ? C : 1) + 64) * 4);
  unsigned short* entC = entA;  // conversion buffer: dead before hop1 writes entA
  int* binbuf = (int*)out;      // coarse-bin buffer lives in d_out (dead until hop0)

  if (hostbits) {
    mini_flag_kernel<<<1, 64, 0, stream>>>(out, hostbits);
    return;
  }

  float* out_ent  = out;
  float* out_drug = out + ent_elems;
  float* out_rel  = out + ent_elems + drug_elems;

  zero_detect_kernel<<<1, 256, 0, stream>>>(
      gcur, nbins, eidx, etype, ent0, flags, n_edges);

  int conv_blocks = (ent_elems / 8 + 255) / 256;
  int part_blocks = (n_edges + 4095) >> 12;
  int rel_blocks  = (rel_elems + 255) / 256;
  int g1 = conv_blocks;
  if (part_blocks > g1) g1 = part_blocks;
  if (rel_blocks > g1) g1 = rel_blocks;
  build1_kernel<<<g1, 256, 0, stream>>>(
      ent0, rel0, eidx, etype, entC, relRaw, relN, out_rel,
      gcur, binbuf, flags, ent_elems, rel_elems, n_ent, n_rel, n_edges,
      nbins, binCap);

  build2_kernel<<<nbins, 256, 0, stream>>>(
      gcur, binbuf, staging, n_ent, binCap, C);

  size_t lds_bytes = (size_t)(n_rel + 1) * D * 4;  // fp32 rel table + zero row
  int hop_blocks = 2048;  // 8 blocks/CU exactly: all co-resident, balanced sweeps
  // hop0: ent0/entC -> v0 bf16 (strided in out_ent); hop1: v0 -> entA (v1 bf16);
  // hop2: entA gather + v0/v1 linear + ent0 -> final out
  hop0_kernel<<<hop_blocks, 256, lds_bytes, stream>>>(
      (const unsigned short*)ent0, entC, relRaw, staging, flags,
      (unsigned short*)out_ent, n_ent, n_rel, C);
  hop1_kernel<<<hop_blocks, 256, lds_bytes, stream>>>(
      (const unsigned short*)out_ent, relN, staging, entA, n_ent, n_rel, C);
  hop2_kernel<<<hop_blocks, 256, lds_bytes, stream>>>(
      entA, relN, staging, ent0, drug0, flags,
      out_ent, out_drug, n_ent, n_drugs, n_rel, C);
}